// Round 11
// baseline (516.689 us; speedup 1.0000x reference)
//
#include <hip/hip_runtime.h>
#include <math.h>

#define F_IN 1433
#define F_HID 16
#define F_OUT 7
#define KSPLIT 8
#define KCHUNK 192  // KSPLIT*KCHUNK >= F_IN; multiple of 32
#define CAP 128     // padded CSR row capacity; max in-degree ~60 for Poisson(32)

__device__ __forceinline__ unsigned short f2bf(float f) {
  unsigned u = __float_as_uint(f);
  u += 0x7fffu + ((u >> 16) & 1u);  // RNE
  return (unsigned short)(u >> 16);
}

__device__ __forceinline__ unsigned pk2(float a, float b) {
  return (unsigned)f2bf(a) | ((unsigned)f2bf(b) << 16);
}

// unpack-accumulate 2 bf16 from one u32 into two float accumulators
__device__ __forceinline__ void upk_add(unsigned u, float& lo, float& hi) {
  lo += __uint_as_float(u << 16);
  hi += __uint_as_float(u & 0xffff0000u);
}

// ---------------- zero degree counters ----------------
__global__ __launch_bounds__(256) void k_zero(int* __restrict__ cnt, int N) {
  int i = blockIdx.x * 256 + threadIdx.x;
  if (i < N) cnt[i] = 0;
}

// ==== FUSED, 1:1 INTERLEAVED: odd blocks scatter, even blocks gemm ==========
// Interleaving keeps a ~50/50 resident mix at all times so the atomic-bound
// scatter (memory-side, VALU/HBM idle) executes UNDER the gemm's time.
__global__ __launch_bounds__(256) void k_fused(
    const float* __restrict__ x, const float* __restrict__ W1,
    const int* __restrict__ src, const int* __restrict__ dst,
    int* __restrict__ cnt, int* __restrict__ csr, float* __restrict__ part,
    int N, int E, int nrb, int nsb) {
  __shared__ float xs[256 * 33];
  const int t = threadIdx.x;
  const int b = blockIdx.x;

  const int half = b >> 1;
  if ((b & 1) && half < nsb) {
    // ---- scatter role: 4 edges/thread, 1024 edges/block ----
    const int base = (half * 256 + t) * 4;
    if (base + 3 < E) {
      const int4 s = *(const int4*)(src + base);
      const int4 d = *(const int4*)(dst + base);
      int r;
      r = atomicAdd(&cnt[d.x], 1); csr[((size_t)d.x << 7) + r] = s.x;
      r = atomicAdd(&cnt[d.y], 1); csr[((size_t)d.y << 7) + r] = s.y;
      r = atomicAdd(&cnt[d.z], 1); csr[((size_t)d.z << 7) + r] = s.z;
      r = atomicAdd(&cnt[d.w], 1); csr[((size_t)d.w << 7) + r] = s.w;
    } else {
      for (int k = base; k < E; ++k) {
        const int d = dst[k];
        const int r = atomicAdd(&cnt[d], 1);
        csr[((size_t)d << 7) + r] = src[k];
      }
    }
    return;
  }

  // ---- gemm role (R6-proven structure): g = gemm block index ----
  const int g = b - min(half + (b & 1), nsb);
  const int chunk = g / nrb;
  const int rb = g - chunk * nrb;
  const int row0 = rb * 256;
  const int row = row0 + t;
  const int kk = t & 31;
  const int r0 = t >> 5;
  const int cbase = chunk * KCHUNK;
  const int kend = min(cbase + KCHUNK, F_IN);

  float acc[F_HID];
#pragma unroll
  for (int j = 0; j < F_HID; ++j) acc[j] = 0.0f;

  float reg[32];
  {
    const int k = cbase + kk;
    const bool kin = (k < kend);
#pragma unroll
    for (int i = 0; i < 32; ++i) {
      const int rg = row0 + r0 + 8 * i;
      reg[i] = (kin && rg < N) ? x[(size_t)rg * F_IN + k] : 0.0f;
    }
  }

  for (int k0 = cbase; k0 < kend; k0 += 32) {
#pragma unroll
    for (int i = 0; i < 32; ++i) xs[(r0 + 8 * i) * 33 + kk] = reg[i];
    __syncthreads();
    const int kn = k0 + 32;
    if (kn < kend) {
      const int k = kn + kk;
      const bool kin = (k < kend);
#pragma unroll
      for (int i = 0; i < 32; ++i) {
        const int rg = row0 + r0 + 8 * i;
        reg[i] = (kin && rg < N) ? x[(size_t)rg * F_IN + k] : 0.0f;
      }
    }
    const int kw = min(32, kend - k0);
    const float* __restrict__ wp = W1 + (size_t)k0 * F_HID;
    if (kw == 32) {
#pragma unroll
      for (int c = 0; c < 32; ++c) {
        const float xv = xs[t * 33 + c];
#pragma unroll
        for (int j = 0; j < F_HID; ++j)
          acc[j] = fmaf(xv, wp[c * F_HID + j], acc[j]);
      }
    } else {
      for (int c = 0; c < kw; ++c) {
        const float xv = xs[t * 33 + c];
#pragma unroll
        for (int j = 0; j < F_HID; ++j)
          acc[j] = fmaf(xv, wp[c * F_HID + j], acc[j]);
      }
    }
    __syncthreads();
  }

  if (row < N) {
    float4* __restrict__ pp =
        (float4*)(part + ((size_t)chunk * N + row) * F_HID);
    pp[0] = make_float4(acc[0], acc[1], acc[2], acc[3]);
    pp[1] = make_float4(acc[4], acc[5], acc[6], acc[7]);
    pp[2] = make_float4(acc[8], acc[9], acc[10], acc[11]);
    pp[3] = make_float4(acc[12], acc[13], acc[14], acc[15]);
  }
}

// ---- reduce K-split partials, scale by dis=rsqrt(deg+1), pack to bf16 ------
__global__ __launch_bounds__(256) void k_red(const float4* __restrict__ part,
                                             const int* __restrict__ cnt,
                                             uint2* __restrict__ h1b, int N) {
  const int idx = blockIdx.x * 256 + threadIdx.x;  // over N*4 float4s
  if (idx >= N * 4) return;
  const int row = idx >> 2;
  const size_t stride = (size_t)N * 4;
  float4 s = part[idx];
#pragma unroll
  for (int c = 1; c < KSPLIT; ++c) {
    const float4 p = part[c * stride + idx];
    s.x += p.x; s.y += p.y; s.z += p.z; s.w += p.w;
  }
  const float sc = rsqrtf((float)(cnt[row] + 1));
  uint2 o;
  o.x = pk2(s.x * sc, s.y * sc);
  o.y = pk2(s.z * sc, s.w * sc);
  h1b[idx] = o;
}

// ---- layer1 gather + node MLP fused: one wave64 per dst node ---------------
__global__ __launch_bounds__(256) void k_agg1n(
    const int* __restrict__ cnt, const int* __restrict__ csr,
    const uint4* __restrict__ h1v, const float* __restrict__ b1,
    const float* __restrict__ W2, uint4* __restrict__ h2v, int N) {
  const int lane = threadIdx.x & 63;
  const int i = blockIdx.x * 4 + (threadIdx.x >> 6);
  if (i >= N) return;
  const int nb = lane >> 1;   // neighbor slot 0..31
  const int p = lane & 1;     // which half of the row

  const int d = cnt[i];
  const int* __restrict__ row = csr + ((size_t)i << 7);

  float a0 = 0.f, a1 = 0.f, a2 = 0.f, a3 = 0.f,
        a4 = 0.f, a5 = 0.f, a6 = 0.f, a7 = 0.f;
  for (int c0 = 0; c0 < d; c0 += 32) {
    const int c = c0 + nb;
    if (c < d) {
      const int s = row[c];
      const uint4 v = h1v[((size_t)s << 1) + p];
      upk_add(v.x, a0, a1);
      upk_add(v.y, a2, a3);
      upk_add(v.z, a4, a5);
      upk_add(v.w, a6, a7);
    }
  }
#pragma unroll
  for (int m = 2; m <= 32; m <<= 1) {
    a0 += __shfl_xor(a0, m); a1 += __shfl_xor(a1, m);
    a2 += __shfl_xor(a2, m); a3 += __shfl_xor(a3, m);
    a4 += __shfl_xor(a4, m); a5 += __shfl_xor(a5, m);
    a6 += __shfl_xor(a6, m); a7 += __shfl_xor(a7, m);
  }
  // self-loop contribution
  {
    const uint4 v = h1v[((size_t)i << 1) + p];
    upk_add(v.x, a0, a1);
    upk_add(v.y, a2, a3);
    upk_add(v.z, a4, a5);
    upk_add(v.w, a6, a7);
  }
  const float sd = rsqrtf((float)(d + 1));
  const float4 bl = ((const float4*)b1)[p * 2];
  const float4 bh = ((const float4*)b1)[p * 2 + 1];
  float t0 = fmaxf(fmaf(a0, sd, bl.x), 0.f);
  float t1 = fmaxf(fmaf(a1, sd, bl.y), 0.f);
  float t2 = fmaxf(fmaf(a2, sd, bl.z), 0.f);
  float t3 = fmaxf(fmaf(a3, sd, bl.w), 0.f);
  float t4 = fmaxf(fmaf(a4, sd, bh.x), 0.f);
  float t5 = fmaxf(fmaf(a5, sd, bh.y), 0.f);
  float t6 = fmaxf(fmaf(a6, sd, bh.z), 0.f);
  float t7 = fmaxf(fmaf(a7, sd, bh.w), 0.f);

  const float* __restrict__ w = W2 + p * 8 * F_OUT;
  float o[F_OUT];
#pragma unroll
  for (int j = 0; j < F_OUT; ++j) {
    o[j] = t0 * w[0 * F_OUT + j] + t1 * w[1 * F_OUT + j] +
           t2 * w[2 * F_OUT + j] + t3 * w[3 * F_OUT + j] +
           t4 * w[4 * F_OUT + j] + t5 * w[5 * F_OUT + j] +
           t6 * w[6 * F_OUT + j] + t7 * w[7 * F_OUT + j];
  }
#pragma unroll
  for (int j = 0; j < F_OUT; ++j) o[j] += __shfl_xor(o[j], 1);

  if (lane == 0) {
    uint4 r;
    r.x = pk2(o[0] * sd, o[1] * sd);
    r.y = pk2(o[2] * sd, o[3] * sd);
    r.z = pk2(o[4] * sd, o[5] * sd);
    r.w = pk2(o[6] * sd, 0.0f);
    h2v[i] = r;
  }
}

// ---- layer2 gather + bias + log_softmax: one wave64 per dst ----------------
__global__ __launch_bounds__(256) void k_agg2n(const int* __restrict__ cnt,
                                               const int* __restrict__ csr,
                                               const uint4* __restrict__ h2v,
                                               const float* __restrict__ b2,
                                               float* __restrict__ out, int N) {
  const int lane = threadIdx.x & 63;
  const int i = blockIdx.x * 4 + (threadIdx.x >> 6);
  if (i >= N) return;

  const int d = cnt[i];
  const int* __restrict__ row = csr + ((size_t)i << 7);

  float a0 = 0.f, a1 = 0.f, a2 = 0.f, a3 = 0.f,
        a4 = 0.f, a5 = 0.f, a6 = 0.f, a7 = 0.f;
  for (int c0 = 0; c0 < d; c0 += 64) {
    const int c = c0 + lane;
    if (c < d) {
      const int s = row[c];
      const uint4 v = h2v[s];
      upk_add(v.x, a0, a1);
      upk_add(v.y, a2, a3);
      upk_add(v.z, a4, a5);
      upk_add(v.w, a6, a7);
    }
  }
#pragma unroll
  for (int m = 1; m <= 32; m <<= 1) {
    a0 += __shfl_xor(a0, m); a1 += __shfl_xor(a1, m);
    a2 += __shfl_xor(a2, m); a3 += __shfl_xor(a3, m);
    a4 += __shfl_xor(a4, m); a5 += __shfl_xor(a5, m);
    a6 += __shfl_xor(a6, m);
  }
  // self-loop
  {
    const uint4 v = h2v[i];
    upk_add(v.x, a0, a1);
    upk_add(v.y, a2, a3);
    upk_add(v.z, a4, a5);
    upk_add(v.w, a6, a7);
  }
  if (lane == 0) {
    const float sd = rsqrtf((float)(d + 1));
    float v0 = fmaf(a0, sd, b2[0]);
    float v1 = fmaf(a1, sd, b2[1]);
    float v2 = fmaf(a2, sd, b2[2]);
    float v3 = fmaf(a3, sd, b2[3]);
    float v4 = fmaf(a4, sd, b2[4]);
    float v5 = fmaf(a5, sd, b2[5]);
    float v6 = fmaf(a6, sd, b2[6]);
    float m = fmaxf(fmaxf(fmaxf(v0, v1), fmaxf(v2, v3)),
                    fmaxf(fmaxf(v4, v5), v6));
    const float sum = expf(v0 - m) + expf(v1 - m) + expf(v2 - m) +
                      expf(v3 - m) + expf(v4 - m) + expf(v5 - m) +
                      expf(v6 - m);
    const float l = m + logf(sum);
    float* __restrict__ op = out + (size_t)i * F_OUT;
    op[0] = v0 - l; op[1] = v1 - l; op[2] = v2 - l; op[3] = v3 - l;
    op[4] = v4 - l; op[5] = v5 - l; op[6] = v6 - l;
  }
}

extern "C" void kernel_launch(void* const* d_in, const int* in_sizes, int n_in,
                              void* d_out, int out_size, void* d_ws,
                              size_t ws_size, hipStream_t stream) {
  const float* x = (const float*)d_in[0];
  const int* ei = (const int*)d_in[1];
  const float* W1 = (const float*)d_in[2];
  const float* b1 = (const float*)d_in[3];
  const float* W2 = (const float*)d_in[4];
  const float* b2 = (const float*)d_in[5];

  const int N = in_sizes[0] / F_IN;
  const int E = in_sizes[1] / 2;
  const int* src = ei;
  const int* dst = ei + E;

  // ws: part[KSPLIT*16N f32] | h1b[16N bf16] | h2b[8N bf16] | cnt[N] | csr[N*CAP]
  float* part = (float*)d_ws;
  unsigned short* h1b = (unsigned short*)(part + (size_t)KSPLIT * 16 * N);
  unsigned short* h2b = h1b + (size_t)16 * N;
  int* cnt = (int*)(h2b + (size_t)8 * N);
  int* csr = cnt + N;
  float* out = (float*)d_out;

  const int B = 256;
  const int nrb = (N + 255) / 256;                 // 391
  const int nsb = (E + 4 * B - 1) / (4 * B);       // 3125 scatter blocks

  k_zero<<<(N + B - 1) / B, B, 0, stream>>>(cnt, N);
  k_fused<<<nsb + nrb * KSPLIT, B, 0, stream>>>(x, W1, src, dst, cnt, csr,
                                                part, N, E, nrb, nsb);
  k_red<<<(N * 4 + B - 1) / B, B, 0, stream>>>((const float4*)part, cnt,
                                               (uint2*)h1b, N);
  k_agg1n<<<(N + 3) / 4, B, 0, stream>>>(cnt, csr, (const uint4*)h1b, b1, W2,
                                         (uint4*)h2b, N);
  k_agg2n<<<(N + 3) / 4, B, 0, stream>>>(cnt, csr, (const uint4*)h2b, b2, out,
                                         N);
}

// Round 12
// 462.952 us; speedup vs baseline: 1.1161x; 1.1161x over previous
//
#include <hip/hip_runtime.h>
#include <math.h>

#define F_IN 1433
#define F_HID 16
#define F_OUT 7
#define KSPLIT 8
#define KCHUNK 192  // KSPLIT*KCHUNK >= F_IN; multiple of 32
#define CAP 128     // padded CSR row capacity; max in-degree ~60 for Poisson(32)
#define NSCAT 512   // long-running grid-stride scatter blocks (dispatched first)

__device__ __forceinline__ unsigned short f2bf(float f) {
  unsigned u = __float_as_uint(f);
  u += 0x7fffu + ((u >> 16) & 1u);  // RNE
  return (unsigned short)(u >> 16);
}

__device__ __forceinline__ unsigned pk2(float a, float b) {
  return (unsigned)f2bf(a) | ((unsigned)f2bf(b) << 16);
}

// unpack-accumulate 2 bf16 from one u32 into two float accumulators
__device__ __forceinline__ void upk_add(unsigned u, float& lo, float& hi) {
  lo += __uint_as_float(u << 16);
  hi += __uint_as_float(u & 0xffff0000u);
}

// ---------------- zero degree counters ----------------
__global__ __launch_bounds__(256) void k_zero(int* __restrict__ cnt, int N) {
  int i = blockIdx.x * 256 + threadIdx.x;
  if (i < N) cnt[i] = 0;
}

// ==== FUSED: blocks [0,NSCAT) = grid-stride scatter (no LDS, dispatched
// first, alive the whole kernel); blocks [NSCAT,..) = K-split GEMM (LDS-
// limited 4/CU). Scatter waves occupy spare wave slots -> true co-residency.
__global__ __launch_bounds__(256) void k_fused(
    const float* __restrict__ x, const float* __restrict__ W1,
    const int* __restrict__ src, const int* __restrict__ dst,
    int* __restrict__ cnt, int* __restrict__ csr, float* __restrict__ part,
    int N, int E, int nrb) {
  const int t = threadIdx.x;
  const int b = blockIdx.x;

  if (b < NSCAT) {
    // ---- scatter role: grid-stride over int4 edge groups ----
    const int ne4 = (E + 3) >> 2;
    for (int i4 = b * 256 + t; i4 < ne4; i4 += NSCAT * 256) {
      const int base = i4 * 4;
      if (base + 3 < E) {
        const int4 s = *(const int4*)(src + base);
        const int4 d = *(const int4*)(dst + base);
        int r;
        r = atomicAdd(&cnt[d.x], 1); csr[((size_t)d.x << 7) + r] = s.x;
        r = atomicAdd(&cnt[d.y], 1); csr[((size_t)d.y << 7) + r] = s.y;
        r = atomicAdd(&cnt[d.z], 1); csr[((size_t)d.z << 7) + r] = s.z;
        r = atomicAdd(&cnt[d.w], 1); csr[((size_t)d.w << 7) + r] = s.w;
      } else {
        for (int k = base; k < E; ++k) {
          const int d = dst[k];
          const int r = atomicAdd(&cnt[d], 1);
          csr[((size_t)d << 7) + r] = src[k];
        }
      }
    }
    return;
  }

  // ---- gemm role (R6-proven structure) ----
  __shared__ float xs[256 * 33];
  const int g = b - NSCAT;
  const int chunk = g / nrb;
  const int rb = g - chunk * nrb;
  const int row0 = rb * 256;
  const int row = row0 + t;
  const int kk = t & 31;
  const int r0 = t >> 5;
  const int cbase = chunk * KCHUNK;
  const int kend = min(cbase + KCHUNK, F_IN);

  float acc[F_HID];
#pragma unroll
  for (int j = 0; j < F_HID; ++j) acc[j] = 0.0f;

  float reg[32];
  {
    const int k = cbase + kk;
    const bool kin = (k < kend);
#pragma unroll
    for (int i = 0; i < 32; ++i) {
      const int rg = row0 + r0 + 8 * i;
      reg[i] = (kin && rg < N) ? x[(size_t)rg * F_IN + k] : 0.0f;
    }
  }

  for (int k0 = cbase; k0 < kend; k0 += 32) {
#pragma unroll
    for (int i = 0; i < 32; ++i) xs[(r0 + 8 * i) * 33 + kk] = reg[i];
    __syncthreads();
    const int kn = k0 + 32;
    if (kn < kend) {
      const int k = kn + kk;
      const bool kin = (k < kend);
#pragma unroll
      for (int i = 0; i < 32; ++i) {
        const int rg = row0 + r0 + 8 * i;
        reg[i] = (kin && rg < N) ? x[(size_t)rg * F_IN + k] : 0.0f;
      }
    }
    const int kw = min(32, kend - k0);
    const float* __restrict__ wp = W1 + (size_t)k0 * F_HID;
    if (kw == 32) {
#pragma unroll
      for (int c = 0; c < 32; ++c) {
        const float xv = xs[t * 33 + c];
#pragma unroll
        for (int j = 0; j < F_HID; ++j)
          acc[j] = fmaf(xv, wp[c * F_HID + j], acc[j]);
      }
    } else {
      for (int c = 0; c < kw; ++c) {
        const float xv = xs[t * 33 + c];
#pragma unroll
        for (int j = 0; j < F_HID; ++j)
          acc[j] = fmaf(xv, wp[c * F_HID + j], acc[j]);
      }
    }
    __syncthreads();
  }

  if (row < N) {
    float4* __restrict__ pp =
        (float4*)(part + ((size_t)chunk * N + row) * F_HID);
    pp[0] = make_float4(acc[0], acc[1], acc[2], acc[3]);
    pp[1] = make_float4(acc[4], acc[5], acc[6], acc[7]);
    pp[2] = make_float4(acc[8], acc[9], acc[10], acc[11]);
    pp[3] = make_float4(acc[12], acc[13], acc[14], acc[15]);
  }
}

// ---- reduce K-split partials, scale by dis=rsqrt(deg+1), pack to bf16 ------
__global__ __launch_bounds__(256) void k_red(const float4* __restrict__ part,
                                             const int* __restrict__ cnt,
                                             uint2* __restrict__ h1b, int N) {
  const int idx = blockIdx.x * 256 + threadIdx.x;  // over N*4 float4s
  if (idx >= N * 4) return;
  const int row = idx >> 2;
  const size_t stride = (size_t)N * 4;
  float4 s = part[idx];
#pragma unroll
  for (int c = 1; c < KSPLIT; ++c) {
    const float4 p = part[c * stride + idx];
    s.x += p.x; s.y += p.y; s.z += p.z; s.w += p.w;
  }
  const float sc = rsqrtf((float)(cnt[row] + 1));
  uint2 o;
  o.x = pk2(s.x * sc, s.y * sc);
  o.y = pk2(s.z * sc, s.w * sc);
  h1b[idx] = o;
}

// ---- layer1 per-node finish: reduce slots, +self, MLP, store bf16 ----------
__device__ __forceinline__ void l1_finish(float a[8], int i, int d, int lane,
                                          int p, const uint4* __restrict__ h1v,
                                          const float* __restrict__ b1,
                                          const float* __restrict__ W2,
                                          uint4* __restrict__ h2v) {
#pragma unroll
  for (int m = 2; m <= 32; m <<= 1) {
#pragma unroll
    for (int j = 0; j < 8; ++j) a[j] += __shfl_xor(a[j], m);
  }
  const uint4 v = h1v[((size_t)i << 1) + p];
  upk_add(v.x, a[0], a[1]);
  upk_add(v.y, a[2], a[3]);
  upk_add(v.z, a[4], a[5]);
  upk_add(v.w, a[6], a[7]);
  const float sd = rsqrtf((float)(d + 1));
  const float4 bl = ((const float4*)b1)[p * 2];
  const float4 bh = ((const float4*)b1)[p * 2 + 1];
  float tt[8];
  tt[0] = fmaxf(fmaf(a[0], sd, bl.x), 0.f);
  tt[1] = fmaxf(fmaf(a[1], sd, bl.y), 0.f);
  tt[2] = fmaxf(fmaf(a[2], sd, bl.z), 0.f);
  tt[3] = fmaxf(fmaf(a[3], sd, bl.w), 0.f);
  tt[4] = fmaxf(fmaf(a[4], sd, bh.x), 0.f);
  tt[5] = fmaxf(fmaf(a[5], sd, bh.y), 0.f);
  tt[6] = fmaxf(fmaf(a[6], sd, bh.z), 0.f);
  tt[7] = fmaxf(fmaf(a[7], sd, bh.w), 0.f);
  const float* __restrict__ w = W2 + p * 8 * F_OUT;
  float o[F_OUT];
#pragma unroll
  for (int j = 0; j < F_OUT; ++j) {
    o[j] = tt[0] * w[0 * F_OUT + j] + tt[1] * w[1 * F_OUT + j] +
           tt[2] * w[2 * F_OUT + j] + tt[3] * w[3 * F_OUT + j] +
           tt[4] * w[4 * F_OUT + j] + tt[5] * w[5 * F_OUT + j] +
           tt[6] * w[6 * F_OUT + j] + tt[7] * w[7 * F_OUT + j];
  }
#pragma unroll
  for (int j = 0; j < F_OUT; ++j) o[j] += __shfl_xor(o[j], 1);
  if (lane == 0) {
    uint4 r;
    r.x = pk2(o[0] * sd, o[1] * sd);
    r.y = pk2(o[2] * sd, o[3] * sd);
    r.z = pk2(o[4] * sd, o[5] * sd);
    r.w = pk2(o[6] * sd, 0.0f);
    h2v[i] = r;
  }
}

// ---- layer1 gather: one wave = TWO nodes (independent gather chains) -------
__global__ __launch_bounds__(256) void k_agg1n(
    const int* __restrict__ cnt, const int* __restrict__ csr,
    const uint4* __restrict__ h1v, const float* __restrict__ b1,
    const float* __restrict__ W2, uint4* __restrict__ h2v, int N) {
  const int lane = threadIdx.x & 63;
  const int i0 = blockIdx.x * 8 + (threadIdx.x >> 6) * 2;
  if (i0 >= N) return;
  const int i1 = i0 + 1;
  const bool has1 = (i1 < N);
  const int nb = lane >> 1;
  const int p = lane & 1;

  const int d0 = cnt[i0];
  const int d1 = has1 ? cnt[i1] : 0;
  const int* __restrict__ row0 = csr + ((size_t)i0 << 7);
  const int* __restrict__ row1 = csr + ((size_t)i1 << 7);

  float A[8], B[8];
#pragma unroll
  for (int j = 0; j < 8; ++j) { A[j] = 0.f; B[j] = 0.f; }
  const int dm = max(d0, d1);
  for (int c0 = 0; c0 < dm; c0 += 32) {
    const int c = c0 + nb;
    if (c < d0) {
      const uint4 v = h1v[((size_t)row0[c] << 1) + p];
      upk_add(v.x, A[0], A[1]); upk_add(v.y, A[2], A[3]);
      upk_add(v.z, A[4], A[5]); upk_add(v.w, A[6], A[7]);
    }
    if (c < d1) {
      const uint4 v = h1v[((size_t)row1[c] << 1) + p];
      upk_add(v.x, B[0], B[1]); upk_add(v.y, B[2], B[3]);
      upk_add(v.z, B[4], B[5]); upk_add(v.w, B[6], B[7]);
    }
  }
  l1_finish(A, i0, d0, lane, p, h1v, b1, W2, h2v);
  if (has1) l1_finish(B, i1, d1, lane, p, h1v, b1, W2, h2v);
}

// ---- layer2 per-node finish: reduce, +self, bias, log_softmax, store -------
__device__ __forceinline__ void l2_finish(float a[8], int i, int d, int lane,
                                          const uint4* __restrict__ h2v,
                                          const float* __restrict__ b2,
                                          float* __restrict__ out) {
#pragma unroll
  for (int m = 1; m <= 32; m <<= 1) {
#pragma unroll
    for (int j = 0; j < 7; ++j) a[j] += __shfl_xor(a[j], m);
  }
  const uint4 v = h2v[i];
  upk_add(v.x, a[0], a[1]);
  upk_add(v.y, a[2], a[3]);
  upk_add(v.z, a[4], a[5]);
  float dummy = 0.f;
  upk_add(v.w, a[6], dummy);
  if (lane == 0) {
    const float sd = rsqrtf((float)(d + 1));
    float vv[7];
#pragma unroll
    for (int j = 0; j < 7; ++j) vv[j] = fmaf(a[j], sd, b2[j]);
    float m = fmaxf(fmaxf(fmaxf(vv[0], vv[1]), fmaxf(vv[2], vv[3])),
                    fmaxf(fmaxf(vv[4], vv[5]), vv[6]));
    float sum = 0.f;
#pragma unroll
    for (int j = 0; j < 7; ++j) sum += expf(vv[j] - m);
    const float l = m + logf(sum);
    float* __restrict__ op = out + (size_t)i * F_OUT;
#pragma unroll
    for (int j = 0; j < 7; ++j) op[j] = vv[j] - l;
  }
}

// ---- layer2 gather: one wave = TWO nodes ----------------------------------
__global__ __launch_bounds__(256) void k_agg2n(const int* __restrict__ cnt,
                                               const int* __restrict__ csr,
                                               const uint4* __restrict__ h2v,
                                               const float* __restrict__ b2,
                                               float* __restrict__ out, int N) {
  const int lane = threadIdx.x & 63;
  const int i0 = blockIdx.x * 8 + (threadIdx.x >> 6) * 2;
  if (i0 >= N) return;
  const int i1 = i0 + 1;
  const bool has1 = (i1 < N);

  const int d0 = cnt[i0];
  const int d1 = has1 ? cnt[i1] : 0;
  const int* __restrict__ row0 = csr + ((size_t)i0 << 7);
  const int* __restrict__ row1 = csr + ((size_t)i1 << 7);

  float A[8], B[8];
#pragma unroll
  for (int j = 0; j < 8; ++j) { A[j] = 0.f; B[j] = 0.f; }
  const int dm = max(d0, d1);
  for (int c0 = 0; c0 < dm; c0 += 64) {
    const int c = c0 + lane;
    if (c < d0) {
      const uint4 v = h2v[row0[c]];
      upk_add(v.x, A[0], A[1]); upk_add(v.y, A[2], A[3]);
      upk_add(v.z, A[4], A[5]); upk_add(v.w, A[6], A[7]);
    }
    if (c < d1) {
      const uint4 v = h2v[row1[c]];
      upk_add(v.x, B[0], B[1]); upk_add(v.y, B[2], B[3]);
      upk_add(v.z, B[4], B[5]); upk_add(v.w, B[6], B[7]);
    }
  }
  l2_finish(A, i0, d0, lane, h2v, b2, out);
  if (has1) l2_finish(B, i1, d1, lane, h2v, b2, out);
}

extern "C" void kernel_launch(void* const* d_in, const int* in_sizes, int n_in,
                              void* d_out, int out_size, void* d_ws,
                              size_t ws_size, hipStream_t stream) {
  const float* x = (const float*)d_in[0];
  const int* ei = (const int*)d_in[1];
  const float* W1 = (const float*)d_in[2];
  const float* b1 = (const float*)d_in[3];
  const float* W2 = (const float*)d_in[4];
  const float* b2 = (const float*)d_in[5];

  const int N = in_sizes[0] / F_IN;
  const int E = in_sizes[1] / 2;
  const int* src = ei;
  const int* dst = ei + E;

  // ws: part[KSPLIT*16N f32] | h1b[16N bf16] | h2b[8N bf16] | cnt[N] | csr[N*CAP]
  float* part = (float*)d_ws;
  unsigned short* h1b = (unsigned short*)(part + (size_t)KSPLIT * 16 * N);
  unsigned short* h2b = h1b + (size_t)16 * N;
  int* cnt = (int*)(h2b + (size_t)8 * N);
  int* csr = cnt + N;
  float* out = (float*)d_out;

  const int B = 256;
  const int nrb = (N + 255) / 256;  // 391

  k_zero<<<(N + B - 1) / B, B, 0, stream>>>(cnt, N);
  k_fused<<<NSCAT + nrb * KSPLIT, B, 0, stream>>>(x, W1, src, dst, cnt, csr,
                                                  part, N, E, nrb);
  k_red<<<(N * 4 + B - 1) / B, B, 0, stream>>>((const float4*)part, cnt,
                                               (uint2*)h1b, N);
  k_agg1n<<<(N + 7) / 8, B, 0, stream>>>(cnt, csr, (const uint4*)h1b, b1, W2,
                                         (uint4*)h2b, N);
  k_agg2n<<<(N + 7) / 8, B, 0, stream>>>(cnt, csr, (const uint4*)h2b, b2, out,
                                         N);
}

// Round 13
// 446.720 us; speedup vs baseline: 1.1566x; 1.0363x over previous
//
#include <hip/hip_runtime.h>
#include <math.h>

#define F_IN 1433
#define F_HID 16
#define F_OUT 7
#define KSPLIT 4
#define KCHUNK 384  // KSPLIT*KCHUNK >= F_IN; multiple of 32
#define CAP 128     // padded CSR row capacity; max in-degree ~60 for Poisson(32)
#define ROWS 128    // gemm rows per block (= block size)
#define NSCAT 1024  // grid-stride scatter blocks (dispatched first)

__device__ __forceinline__ unsigned short f2bf(float f) {
  unsigned u = __float_as_uint(f);
  u += 0x7fffu + ((u >> 16) & 1u);  // RNE
  return (unsigned short)(u >> 16);
}

__device__ __forceinline__ unsigned pk2(float a, float b) {
  return (unsigned)f2bf(a) | ((unsigned)f2bf(b) << 16);
}

// unpack-accumulate 2 bf16 from one u32 into two float accumulators
__device__ __forceinline__ void upk_add(unsigned u, float& lo, float& hi) {
  lo += __uint_as_float(u << 16);
  hi += __uint_as_float(u & 0xffff0000u);
}

// ---------------- zero degree counters ----------------
__global__ __launch_bounds__(256) void k_zero(int* __restrict__ cnt, int N) {
  int i = blockIdx.x * 256 + threadIdx.x;
  if (i < N) cnt[i] = 0;
}

// ==== FUSED: blocks [0,NSCAT) = grid-stride scatter; rest = K-split GEMM ====
// 128-thread blocks; gemm tile 128x(32-col) with 16.9KB LDS -> ~9 blocks/CU
// co-resident = 9 independent barrier domains (vs 4 at 256-row), so one
// block's prefetch hides under other blocks' compute.
__global__ __launch_bounds__(128) void k_fused(
    const float* __restrict__ x, const float* __restrict__ W1,
    const int* __restrict__ src, const int* __restrict__ dst,
    int* __restrict__ cnt, int* __restrict__ csr, float* __restrict__ part,
    int N, int E, int nrb) {
  const int t = threadIdx.x;
  const int b = blockIdx.x;

  if (b < NSCAT) {
    // ---- scatter role: grid-stride over int4 edge groups ----
    const int ne4 = (E + 3) >> 2;
    for (int i4 = b * 128 + t; i4 < ne4; i4 += NSCAT * 128) {
      const int base = i4 * 4;
      if (base + 3 < E) {
        const int4 s = *(const int4*)(src + base);
        const int4 d = *(const int4*)(dst + base);
        int r;
        r = atomicAdd(&cnt[d.x], 1); csr[((size_t)d.x << 7) + r] = s.x;
        r = atomicAdd(&cnt[d.y], 1); csr[((size_t)d.y << 7) + r] = s.y;
        r = atomicAdd(&cnt[d.z], 1); csr[((size_t)d.z << 7) + r] = s.z;
        r = atomicAdd(&cnt[d.w], 1); csr[((size_t)d.w << 7) + r] = s.w;
      } else {
        for (int k = base; k < E; ++k) {
          const int d = dst[k];
          const int r = atomicAdd(&cnt[d], 1);
          csr[((size_t)d << 7) + r] = src[k];
        }
      }
    }
    return;
  }

  // ---- gemm role: part[chunk][row][j] += over K-chunk ----
  __shared__ float xs[ROWS * 33];
  const int g = b - NSCAT;
  const int chunk = g / nrb;
  const int rb = g - chunk * nrb;
  const int row0 = rb * ROWS;
  const int row = row0 + t;
  const int kk = t & 31;
  const int r0 = t >> 5;  // 0..3
  const int cbase = chunk * KCHUNK;
  const int kend = min(cbase + KCHUNK, F_IN);

  float acc[F_HID];
#pragma unroll
  for (int j = 0; j < F_HID; ++j) acc[j] = 0.0f;

  float reg[32];
  {
    const int k = cbase + kk;
    const bool kin = (k < kend);
#pragma unroll
    for (int i = 0; i < 32; ++i) {
      const int rg = row0 + r0 + 4 * i;
      reg[i] = (kin && rg < N) ? x[(size_t)rg * F_IN + k] : 0.0f;
    }
  }

  for (int k0 = cbase; k0 < kend; k0 += 32) {
#pragma unroll
    for (int i = 0; i < 32; ++i) xs[(r0 + 4 * i) * 33 + kk] = reg[i];
    __syncthreads();
    const int kn = k0 + 32;
    if (kn < kend) {
      const int k = kn + kk;
      const bool kin = (k < kend);
#pragma unroll
      for (int i = 0; i < 32; ++i) {
        const int rg = row0 + r0 + 4 * i;
        reg[i] = (kin && rg < N) ? x[(size_t)rg * F_IN + k] : 0.0f;
      }
    }
    const int kw = min(32, kend - k0);
    const float* __restrict__ wp = W1 + (size_t)k0 * F_HID;
    if (kw == 32) {
#pragma unroll
      for (int c = 0; c < 32; ++c) {
        const float xv = xs[t * 33 + c];
#pragma unroll
        for (int j = 0; j < F_HID; ++j)
          acc[j] = fmaf(xv, wp[c * F_HID + j], acc[j]);
      }
    } else {
      for (int c = 0; c < kw; ++c) {
        const float xv = xs[t * 33 + c];
#pragma unroll
        for (int j = 0; j < F_HID; ++j)
          acc[j] = fmaf(xv, wp[c * F_HID + j], acc[j]);
      }
    }
    __syncthreads();
  }

  if (row < N) {
    float4* __restrict__ pp =
        (float4*)(part + ((size_t)chunk * N + row) * F_HID);
    pp[0] = make_float4(acc[0], acc[1], acc[2], acc[3]);
    pp[1] = make_float4(acc[4], acc[5], acc[6], acc[7]);
    pp[2] = make_float4(acc[8], acc[9], acc[10], acc[11]);
    pp[3] = make_float4(acc[12], acc[13], acc[14], acc[15]);
  }
}

// ---- reduce K-split partials, scale by dis=rsqrt(deg+1), pack to bf16 ------
__global__ __launch_bounds__(256) void k_red(const float4* __restrict__ part,
                                             const int* __restrict__ cnt,
                                             uint2* __restrict__ h1b, int N) {
  const int idx = blockIdx.x * 256 + threadIdx.x;  // over N*4 float4s
  if (idx >= N * 4) return;
  const int row = idx >> 2;
  const size_t stride = (size_t)N * 4;
  float4 s = part[idx];
#pragma unroll
  for (int c = 1; c < KSPLIT; ++c) {
    const float4 p = part[c * stride + idx];
    s.x += p.x; s.y += p.y; s.z += p.z; s.w += p.w;
  }
  const float sc = rsqrtf((float)(cnt[row] + 1));
  uint2 o;
  o.x = pk2(s.x * sc, s.y * sc);
  o.y = pk2(s.z * sc, s.w * sc);
  h1b[idx] = o;
}

// ---- layer1 per-node finish: reduce slots, +self, MLP, store bf16 ----------
__device__ __forceinline__ void l1_finish(float a[8], int i, int d, int lane,
                                          int p, const uint4* __restrict__ h1v,
                                          const float* __restrict__ b1,
                                          const float* __restrict__ W2,
                                          uint4* __restrict__ h2v) {
#pragma unroll
  for (int m = 2; m <= 32; m <<= 1) {
#pragma unroll
    for (int j = 0; j < 8; ++j) a[j] += __shfl_xor(a[j], m);
  }
  const uint4 v = h1v[((size_t)i << 1) + p];
  upk_add(v.x, a[0], a[1]);
  upk_add(v.y, a[2], a[3]);
  upk_add(v.z, a[4], a[5]);
  upk_add(v.w, a[6], a[7]);
  const float sd = rsqrtf((float)(d + 1));
  const float4 bl = ((const float4*)b1)[p * 2];
  const float4 bh = ((const float4*)b1)[p * 2 + 1];
  float tt[8];
  tt[0] = fmaxf(fmaf(a[0], sd, bl.x), 0.f);
  tt[1] = fmaxf(fmaf(a[1], sd, bl.y), 0.f);
  tt[2] = fmaxf(fmaf(a[2], sd, bl.z), 0.f);
  tt[3] = fmaxf(fmaf(a[3], sd, bl.w), 0.f);
  tt[4] = fmaxf(fmaf(a[4], sd, bh.x), 0.f);
  tt[5] = fmaxf(fmaf(a[5], sd, bh.y), 0.f);
  tt[6] = fmaxf(fmaf(a[6], sd, bh.z), 0.f);
  tt[7] = fmaxf(fmaf(a[7], sd, bh.w), 0.f);
  const float* __restrict__ w = W2 + p * 8 * F_OUT;
  float o[F_OUT];
#pragma unroll
  for (int j = 0; j < F_OUT; ++j) {
    o[j] = tt[0] * w[0 * F_OUT + j] + tt[1] * w[1 * F_OUT + j] +
           tt[2] * w[2 * F_OUT + j] + tt[3] * w[3 * F_OUT + j] +
           tt[4] * w[4 * F_OUT + j] + tt[5] * w[5 * F_OUT + j] +
           tt[6] * w[6 * F_OUT + j] + tt[7] * w[7 * F_OUT + j];
  }
#pragma unroll
  for (int j = 0; j < F_OUT; ++j) o[j] += __shfl_xor(o[j], 1);
  if (lane == 0) {
    uint4 r;
    r.x = pk2(o[0] * sd, o[1] * sd);
    r.y = pk2(o[2] * sd, o[3] * sd);
    r.z = pk2(o[4] * sd, o[5] * sd);
    r.w = pk2(o[6] * sd, 0.0f);
    h2v[i] = r;
  }
}

// ---- layer1 gather: one wave = TWO nodes (independent gather chains) -------
__global__ __launch_bounds__(256) void k_agg1n(
    const int* __restrict__ cnt, const int* __restrict__ csr,
    const uint4* __restrict__ h1v, const float* __restrict__ b1,
    const float* __restrict__ W2, uint4* __restrict__ h2v, int N) {
  const int lane = threadIdx.x & 63;
  const int i0 = blockIdx.x * 8 + (threadIdx.x >> 6) * 2;
  if (i0 >= N) return;
  const int i1 = i0 + 1;
  const bool has1 = (i1 < N);
  const int nb = lane >> 1;
  const int p = lane & 1;

  const int d0 = cnt[i0];
  const int d1 = has1 ? cnt[i1] : 0;
  const int* __restrict__ row0 = csr + ((size_t)i0 << 7);
  const int* __restrict__ row1 = csr + ((size_t)i1 << 7);

  float A[8], B[8];
#pragma unroll
  for (int j = 0; j < 8; ++j) { A[j] = 0.f; B[j] = 0.f; }
  const int dm = max(d0, d1);
  for (int c0 = 0; c0 < dm; c0 += 32) {
    const int c = c0 + nb;
    if (c < d0) {
      const uint4 v = h1v[((size_t)row0[c] << 1) + p];
      upk_add(v.x, A[0], A[1]); upk_add(v.y, A[2], A[3]);
      upk_add(v.z, A[4], A[5]); upk_add(v.w, A[6], A[7]);
    }
    if (c < d1) {
      const uint4 v = h1v[((size_t)row1[c] << 1) + p];
      upk_add(v.x, B[0], B[1]); upk_add(v.y, B[2], B[3]);
      upk_add(v.z, B[4], B[5]); upk_add(v.w, B[6], B[7]);
    }
  }
  l1_finish(A, i0, d0, lane, p, h1v, b1, W2, h2v);
  if (has1) l1_finish(B, i1, d1, lane, p, h1v, b1, W2, h2v);
}

// ---- layer2 per-node finish: reduce, +self, bias, log_softmax, store -------
__device__ __forceinline__ void l2_finish(float a[8], int i, int d, int lane,
                                          const uint4* __restrict__ h2v,
                                          const float* __restrict__ b2,
                                          float* __restrict__ out) {
#pragma unroll
  for (int m = 1; m <= 32; m <<= 1) {
#pragma unroll
    for (int j = 0; j < 7; ++j) a[j] += __shfl_xor(a[j], m);
  }
  const uint4 v = h2v[i];
  upk_add(v.x, a[0], a[1]);
  upk_add(v.y, a[2], a[3]);
  upk_add(v.z, a[4], a[5]);
  float dummy = 0.f;
  upk_add(v.w, a[6], dummy);
  if (lane == 0) {
    const float sd = rsqrtf((float)(d + 1));
    float vv[7];
#pragma unroll
    for (int j = 0; j < 7; ++j) vv[j] = fmaf(a[j], sd, b2[j]);
    float m = fmaxf(fmaxf(fmaxf(vv[0], vv[1]), fmaxf(vv[2], vv[3])),
                    fmaxf(fmaxf(vv[4], vv[5]), vv[6]));
    float sum = 0.f;
#pragma unroll
    for (int j = 0; j < 7; ++j) sum += expf(vv[j] - m);
    const float l = m + logf(sum);
    float* __restrict__ op = out + (size_t)i * F_OUT;
#pragma unroll
    for (int j = 0; j < 7; ++j) op[j] = vv[j] - l;
  }
}

// ---- layer2 gather: one wave = TWO nodes ----------------------------------
__global__ __launch_bounds__(256) void k_agg2n(const int* __restrict__ cnt,
                                               const int* __restrict__ csr,
                                               const uint4* __restrict__ h2v,
                                               const float* __restrict__ b2,
                                               float* __restrict__ out, int N) {
  const int lane = threadIdx.x & 63;
  const int i0 = blockIdx.x * 8 + (threadIdx.x >> 6) * 2;
  if (i0 >= N) return;
  const int i1 = i0 + 1;
  const bool has1 = (i1 < N);

  const int d0 = cnt[i0];
  const int d1 = has1 ? cnt[i1] : 0;
  const int* __restrict__ row0 = csr + ((size_t)i0 << 7);
  const int* __restrict__ row1 = csr + ((size_t)i1 << 7);

  float A[8], B[8];
#pragma unroll
  for (int j = 0; j < 8; ++j) { A[j] = 0.f; B[j] = 0.f; }
  const int dm = max(d0, d1);
  for (int c0 = 0; c0 < dm; c0 += 64) {
    const int c = c0 + lane;
    if (c < d0) {
      const uint4 v = h2v[row0[c]];
      upk_add(v.x, A[0], A[1]); upk_add(v.y, A[2], A[3]);
      upk_add(v.z, A[4], A[5]); upk_add(v.w, A[6], A[7]);
    }
    if (c < d1) {
      const uint4 v = h2v[row1[c]];
      upk_add(v.x, B[0], B[1]); upk_add(v.y, B[2], B[3]);
      upk_add(v.z, B[4], B[5]); upk_add(v.w, B[6], B[7]);
    }
  }
  l2_finish(A, i0, d0, lane, h2v, b2, out);
  if (has1) l2_finish(B, i1, d1, lane, h2v, b2, out);
}

extern "C" void kernel_launch(void* const* d_in, const int* in_sizes, int n_in,
                              void* d_out, int out_size, void* d_ws,
                              size_t ws_size, hipStream_t stream) {
  const float* x = (const float*)d_in[0];
  const int* ei = (const int*)d_in[1];
  const float* W1 = (const float*)d_in[2];
  const float* b1 = (const float*)d_in[3];
  const float* W2 = (const float*)d_in[4];
  const float* b2 = (const float*)d_in[5];

  const int N = in_sizes[0] / F_IN;
  const int E = in_sizes[1] / 2;
  const int* src = ei;
  const int* dst = ei + E;

  // ws: part[KSPLIT*16N f32] | h1b[16N bf16] | h2b[8N bf16] | cnt[N] | csr[N*CAP]
  float* part = (float*)d_ws;
  unsigned short* h1b = (unsigned short*)(part + (size_t)KSPLIT * 16 * N);
  unsigned short* h2b = h1b + (size_t)16 * N;
  int* cnt = (int*)(h2b + (size_t)8 * N);
  int* csr = cnt + N;
  float* out = (float*)d_out;

  const int B = 256;
  const int nrb = (N + ROWS - 1) / ROWS;  // 782

  k_zero<<<(N + B - 1) / B, B, 0, stream>>>(cnt, N);
  k_fused<<<NSCAT + nrb * KSPLIT, 128, 0, stream>>>(x, W1, src, dst, cnt, csr,
                                                    part, N, E, nrb);
  k_red<<<(N * 4 + B - 1) / B, B, 0, stream>>>((const float4*)part, cnt,
                                               (uint2*)h1b, N);
  k_agg1n<<<(N + 7) / 8, B, 0, stream>>>(cnt, csr, (const uint4*)h1b, b1, W2,
                                         (uint4*)h2b, N);
  k_agg2n<<<(N + 7) / 8, B, 0, stream>>>(cnt, csr, (const uint4*)h2b, b2, out,
                                         N);
}

// Round 15
// 410.324 us; speedup vs baseline: 1.2592x; 1.0887x over previous
//
#include <hip/hip_runtime.h>
#include <math.h>

#define F_IN 1433
#define F_HID 16
#define F_OUT 7
#define CAP 128     // padded CSR row capacity; max in-degree ~60 for Poisson(32)
#define NSCAT 512   // grid-stride scatter blocks (dispatched first)
#define NKT 45      // ceil(1433/32) k-tiles
#define KTFULL 44   // full 32-wide k-tiles

typedef __attribute__((ext_vector_type(8))) short bf16x8;
typedef __attribute__((ext_vector_type(4))) float f32x4;

__device__ __forceinline__ unsigned short f2bf(float f) {
  unsigned u = __float_as_uint(f);
  u += 0x7fffu + ((u >> 16) & 1u);  // RNE
  return (unsigned short)(u >> 16);
}

__device__ __forceinline__ unsigned pk2(float a, float b) {
  return (unsigned)f2bf(a) | ((unsigned)f2bf(b) << 16);
}

__device__ __forceinline__ void upk_add(unsigned u, float& lo, float& hi) {
  lo += __uint_as_float(u << 16);
  hi += __uint_as_float(u & 0xffff0000u);
}

// ---- prep: zero cnt (blocks [0,nzb)) + pack W1 into B-fragment order -------
// W1f[tile][lane] = 8 bf16 {W1[tile*32 + (lane>>4)*8 + j][lane&15]}, j=0..7
__global__ __launch_bounds__(256) void k_prep(const float* __restrict__ W1,
                                              int* __restrict__ cnt,
                                              uint4* __restrict__ W1f, int N,
                                              int nzb) {
  const int b = blockIdx.x, t = threadIdx.x;
  if (b < nzb) {
    const int i = b * 256 + t;
    if (i < N) cnt[i] = 0;
    return;
  }
  if (t >= 64) return;
  const int tile = b - nzb;
  const int kg = t >> 4, n = t & 15;
  unsigned u[4];
#pragma unroll
  for (int p = 0; p < 4; ++p) {
    const int k0 = tile * 32 + kg * 8 + 2 * p;
    const float a = (k0 < F_IN) ? W1[k0 * F_HID + n] : 0.0f;
    const float bb = (k0 + 1 < F_IN) ? W1[(k0 + 1) * F_HID + n] : 0.0f;
    u[p] = pk2(a, bb);
  }
  W1f[tile * 64 + t] = make_uint4(u[0], u[1], u[2], u[3]);
}

// ==== FUSED: blocks [0,NSCAT) = grid-stride CSR scatter; rest = MFMA GEMM ===
// GEMM: one wave per 16-row m-tile, full K. A = x rows cast to bf16 in-regs
// (2 contiguous float4 loads/lane, NO LDS, NO barriers); B = W1f from L2.
__global__ __launch_bounds__(256) void k_fused(
    const float* __restrict__ x, const uint4* __restrict__ W1f,
    const int* __restrict__ src, const int* __restrict__ dst,
    int* __restrict__ cnt, int* __restrict__ csr, float* __restrict__ h1f,
    int N, int E) {
  const int t = threadIdx.x;
  const int b = blockIdx.x;

  if (b < NSCAT) {
    const int ne4 = (E + 3) >> 2;
    for (int i4 = b * 256 + t; i4 < ne4; i4 += NSCAT * 256) {
      const int base = i4 * 4;
      if (base + 3 < E) {
        const int4 s = *(const int4*)(src + base);
        const int4 d = *(const int4*)(dst + base);
        int r;
        r = atomicAdd(&cnt[d.x], 1); csr[((size_t)d.x << 7) + r] = s.x;
        r = atomicAdd(&cnt[d.y], 1); csr[((size_t)d.y << 7) + r] = s.y;
        r = atomicAdd(&cnt[d.z], 1); csr[((size_t)d.z << 7) + r] = s.z;
        r = atomicAdd(&cnt[d.w], 1); csr[((size_t)d.w << 7) + r] = s.w;
      } else {
        for (int k = base; k < E; ++k) {
          const int d = dst[k];
          const int r = atomicAdd(&cnt[d], 1);
          csr[((size_t)d << 7) + r] = src[k];
        }
      }
    }
    return;
  }

  // ---- gemm role ----
  const int g = b - NSCAT;
  const int w = t >> 6;
  const int l = t & 63;
  const int mtile = g * 4 + w;
  const int row0 = mtile * 16;
  if (row0 >= N) return;
  const int m = l & 15;   // A row within tile (node)
  const int kg = l >> 4;  // k-group 0..3
  int row = row0 + m;
  if (row >= N) row = N - 1;  // clamp for loads; stores guarded below
  const float* __restrict__ xr = x + (size_t)row * F_IN;

  f32x4 acc = {0.f, 0.f, 0.f, 0.f};
  for (int kt = 0; kt < KTFULL; ++kt) {
    const int k0 = kt * 32 + kg * 8;
    const float4 xa = *(const float4*)(xr + k0);
    const float4 xb = *(const float4*)(xr + k0 + 4);
    union { unsigned u[4]; bf16x8 v; } av;
    av.u[0] = pk2(xa.x, xa.y);
    av.u[1] = pk2(xa.z, xa.w);
    av.u[2] = pk2(xb.x, xb.y);
    av.u[3] = pk2(xb.z, xb.w);
    union { uint4 q; bf16x8 v; } wv;
    wv.q = W1f[kt * 64 + l];
    acc = __builtin_amdgcn_mfma_f32_16x16x32_bf16(av.v, wv.v, acc, 0, 0, 0);
  }
  {  // tail k-tile (k >= 1408), zero-padded per element
    const int k0 = KTFULL * 32 + kg * 8;
    float e[8];
#pragma unroll
    for (int j = 0; j < 8; ++j) {
      const int k = k0 + j;
      e[j] = (k < F_IN) ? xr[k] : 0.0f;
    }
    union { unsigned u[4]; bf16x8 v; } av;
    av.u[0] = pk2(e[0], e[1]);
    av.u[1] = pk2(e[2], e[3]);
    av.u[2] = pk2(e[4], e[5]);
    av.u[3] = pk2(e[6], e[7]);
    union { uint4 q; bf16x8 v; } wv;
    wv.q = W1f[KTFULL * 64 + l];
    acc = __builtin_amdgcn_mfma_f32_16x16x32_bf16(av.v, wv.v, acc, 0, 0, 0);
  }
  // C/D layout (m89-verified): col = l&15 (feature), row = (l>>4)*4 + r (node)
#pragma unroll
  for (int r = 0; r < 4; ++r) {
    const int orow = row0 + kg * 4 + r;
    if (orow < N) h1f[(size_t)orow * F_HID + m] = acc[r];
  }
}

// ---- scale h1f by dis=rsqrt(deg+1), pack to bf16 (uint4 = 8 bf16) ----------
__global__ __launch_bounds__(256) void k_scale(const float4* __restrict__ h1f,
                                               const int* __restrict__ cnt,
                                               uint4* __restrict__ h1v, int N) {
  const int idx = blockIdx.x * 256 + threadIdx.x;  // over 2N halves
  if (idx >= 2 * N) return;
  const int node = idx >> 1;
  const float sc = rsqrtf((float)(cnt[node] + 1));
  const float4 a = h1f[idx * 2];
  const float4 b = h1f[idx * 2 + 1];
  uint4 o;
  o.x = pk2(a.x * sc, a.y * sc);
  o.y = pk2(a.z * sc, a.w * sc);
  o.z = pk2(b.x * sc, b.y * sc);
  o.w = pk2(b.z * sc, b.w * sc);
  h1v[idx] = o;
}

// ---- layer1 per-node finish: reduce slots, +self, MLP, store bf16 ----------
__device__ __forceinline__ void l1_finish(float a[8], int i, int d, int lane,
                                          int p, const uint4* __restrict__ h1v,
                                          const float* __restrict__ b1,
                                          const float* __restrict__ W2,
                                          uint4* __restrict__ h2v) {
#pragma unroll
  for (int m = 2; m <= 32; m <<= 1) {
#pragma unroll
    for (int j = 0; j < 8; ++j) a[j] += __shfl_xor(a[j], m);
  }
  const uint4 v = h1v[((size_t)i << 1) + p];
  upk_add(v.x, a[0], a[1]);
  upk_add(v.y, a[2], a[3]);
  upk_add(v.z, a[4], a[5]);
  upk_add(v.w, a[6], a[7]);
  const float sd = rsqrtf((float)(d + 1));
  const float4 bl = ((const float4*)b1)[p * 2];
  const float4 bh = ((const float4*)b1)[p * 2 + 1];
  float tt[8];
  tt[0] = fmaxf(fmaf(a[0], sd, bl.x), 0.f);
  tt[1] = fmaxf(fmaf(a[1], sd, bl.y), 0.f);
  tt[2] = fmaxf(fmaf(a[2], sd, bl.z), 0.f);
  tt[3] = fmaxf(fmaf(a[3], sd, bl.w), 0.f);
  tt[4] = fmaxf(fmaf(a[4], sd, bh.x), 0.f);
  tt[5] = fmaxf(fmaf(a[5], sd, bh.y), 0.f);
  tt[6] = fmaxf(fmaf(a[6], sd, bh.z), 0.f);
  tt[7] = fmaxf(fmaf(a[7], sd, bh.w), 0.f);
  const float* __restrict__ w = W2 + p * 8 * F_OUT;
  float o[F_OUT];
#pragma unroll
  for (int j = 0; j < F_OUT; ++j) {
    o[j] = tt[0] * w[0 * F_OUT + j] + tt[1] * w[1 * F_OUT + j] +
           tt[2] * w[2 * F_OUT + j] + tt[3] * w[3 * F_OUT + j] +
           tt[4] * w[4 * F_OUT + j] + tt[5] * w[5 * F_OUT + j] +
           tt[6] * w[6 * F_OUT + j] + tt[7] * w[7 * F_OUT + j];
  }
#pragma unroll
  for (int j = 0; j < F_OUT; ++j) o[j] += __shfl_xor(o[j], 1);
  if (lane == 0) {
    uint4 r;
    r.x = pk2(o[0] * sd, o[1] * sd);
    r.y = pk2(o[2] * sd, o[3] * sd);
    r.z = pk2(o[4] * sd, o[5] * sd);
    r.w = pk2(o[6] * sd, 0.0f);
    h2v[i] = r;
  }
}

// ---- layer1 gather: one wave = TWO nodes (independent gather chains) -------
__global__ __launch_bounds__(256) void k_agg1n(
    const int* __restrict__ cnt, const int* __restrict__ csr,
    const uint4* __restrict__ h1v, const float* __restrict__ b1,
    const float* __restrict__ W2, uint4* __restrict__ h2v, int N) {
  const int lane = threadIdx.x & 63;
  const int i0 = blockIdx.x * 8 + (threadIdx.x >> 6) * 2;
  if (i0 >= N) return;
  const int i1 = i0 + 1;
  const bool has1 = (i1 < N);
  const int nb = lane >> 1;
  const int p = lane & 1;

  const int d0 = cnt[i0];
  const int d1 = has1 ? cnt[i1] : 0;
  const int* __restrict__ row0 = csr + ((size_t)i0 << 7);
  const int* __restrict__ row1 = csr + ((size_t)i1 << 7);

  float A[8], B[8];
#pragma unroll
  for (int j = 0; j < 8; ++j) { A[j] = 0.f; B[j] = 0.f; }
  const int dm = max(d0, d1);
  for (int c0 = 0; c0 < dm; c0 += 32) {
    const int c = c0 + nb;
    if (c < d0) {
      const uint4 v = h1v[((size_t)row0[c] << 1) + p];
      upk_add(v.x, A[0], A[1]); upk_add(v.y, A[2], A[3]);
      upk_add(v.z, A[4], A[5]); upk_add(v.w, A[6], A[7]);
    }
    if (c < d1) {
      const uint4 v = h1v[((size_t)row1[c] << 1) + p];
      upk_add(v.x, B[0], B[1]); upk_add(v.y, B[2], B[3]);
      upk_add(v.z, B[4], B[5]); upk_add(v.w, B[6], B[7]);
    }
  }
  l1_finish(A, i0, d0, lane, p, h1v, b1, W2, h2v);
  if (has1) l1_finish(B, i1, d1, lane, p, h1v, b1, W2, h2v);
}

// ---- layer2 per-node finish: reduce, +self, bias, log_softmax, store -------
__device__ __forceinline__ void l2_finish(float a[8], int i, int d, int lane,
                                          const uint4* __restrict__ h2v,
                                          const float* __restrict__ b2,
                                          float* __restrict__ out) {
#pragma unroll
  for (int m = 1; m <= 32; m <<= 1) {
#pragma unroll
    for (int j = 0; j < 7; ++j) a[j] += __shfl_xor(a[j], m);
  }
  const uint4 v = h2v[i];
  upk_add(v.x, a[0], a[1]);
  upk_add(v.y, a[2], a[3]);
  upk_add(v.z, a[4], a[5]);
  float dummy = 0.f;
  upk_add(v.w, a[6], dummy);
  if (lane == 0) {
    const float sd = rsqrtf((float)(d + 1));
    float vv[7];
#pragma unroll
    for (int j = 0; j < 7; ++j) vv[j] = fmaf(a[j], sd, b2[j]);
    float m = fmaxf(fmaxf(fmaxf(vv[0], vv[1]), fmaxf(vv[2], vv[3])),
                    fmaxf(fmaxf(vv[4], vv[5]), vv[6]));
    float sum = 0.f;
#pragma unroll
    for (int j = 0; j < 7; ++j) sum += expf(vv[j] - m);
    const float l = m + logf(sum);
    float* __restrict__ op = out + (size_t)i * F_OUT;
#pragma unroll
    for (int j = 0; j < 7; ++j) op[j] = vv[j] - l;
  }
}

// ---- layer2 gather: one wave = TWO nodes ----------------------------------
__global__ __launch_bounds__(256) void k_agg2n(const int* __restrict__ cnt,
                                               const int* __restrict__ csr,
                                               const uint4* __restrict__ h2v,
                                               const float* __restrict__ b2,
                                               float* __restrict__ out, int N) {
  const int lane = threadIdx.x & 63;
  const int i0 = blockIdx.x * 8 + (threadIdx.x >> 6) * 2;
  if (i0 >= N) return;
  const int i1 = i0 + 1;
  const bool has1 = (i1 < N);

  const int d0 = cnt[i0];
  const int d1 = has1 ? cnt[i1] : 0;
  const int* __restrict__ row0 = csr + ((size_t)i0 << 7);
  const int* __restrict__ row1 = csr + ((size_t)i1 << 7);

  float A[8], B[8];
#pragma unroll
  for (int j = 0; j < 8; ++j) { A[j] = 0.f; B[j] = 0.f; }
  const int dm = max(d0, d1);
  for (int c0 = 0; c0 < dm; c0 += 64) {
    const int c = c0 + lane;
    if (c < d0) {
      const uint4 v = h2v[row0[c]];
      upk_add(v.x, A[0], A[1]); upk_add(v.y, A[2], A[3]);
      upk_add(v.z, A[4], A[5]); upk_add(v.w, A[6], A[7]);
    }
    if (c < d1) {
      const uint4 v = h2v[row1[c]];
      upk_add(v.x, B[0], B[1]); upk_add(v.y, B[2], B[3]);
      upk_add(v.z, B[4], B[5]); upk_add(v.w, B[6], B[7]);
    }
  }
  l2_finish(A, i0, d0, lane, h2v, b2, out);
  if (has1) l2_finish(B, i1, d1, lane, h2v, b2, out);
}

extern "C" void kernel_launch(void* const* d_in, const int* in_sizes, int n_in,
                              void* d_out, int out_size, void* d_ws,
                              size_t ws_size, hipStream_t stream) {
  const float* x = (const float*)d_in[0];
  const int* ei = (const int*)d_in[1];
  const float* W1 = (const float*)d_in[2];
  const float* b1 = (const float*)d_in[3];
  const float* W2 = (const float*)d_in[4];
  const float* b2 = (const float*)d_in[5];

  const int N = in_sizes[0] / F_IN;
  const int E = in_sizes[1] / 2;
  const int* src = ei;
  const int* dst = ei + E;

  // ws: h1f[16N f32] | h1b[16N bf16] | h2b[8N bf16] | cnt[N] | csr[N*CAP] | W1f
  float* h1f = (float*)d_ws;
  unsigned short* h1b = (unsigned short*)(h1f + (size_t)16 * N);
  unsigned short* h2b = h1b + (size_t)16 * N;
  int* cnt = (int*)(h2b + (size_t)8 * N);
  int* csr = cnt + N;
  uint4* W1f = (uint4*)(csr + (size_t)N * CAP);
  float* out = (float*)d_out;

  const int B = 256;
  const int nzb = (N + B - 1) / B;               // 391
  const int ngb = ((N + 15) / 16 + 3) / 4;       // gemm blocks: 4 m-tiles each

  k_prep<<<nzb + NKT, B, 0, stream>>>(W1, cnt, W1f, N, nzb);
  k_fused<<<NSCAT + ngb, B, 0, stream>>>(x, W1f, src, dst, cnt, csr, h1f, N, E);
  k_scale<<<(2 * N + B - 1) / B, B, 0, stream>>>((const float4*)h1f, cnt,
                                                 (uint4*)h1b, N);
  k_agg1n<<<(N + 7) / 8, B, 0, stream>>>(cnt, csr, (const uint4*)h1b, b1, W2,
                                         (uint4*)h2b, N);
  k_agg2n<<<(N + 7) / 8, B, 0, stream>>>(cnt, csr, (const uint4*)h2b, b2, out,
                                         N);
}